// Round 1
// baseline (13.138 us; speedup 1.0000x reference)
//
#include <hip/hip_runtime.h>

// RBFLayer: B=4, N=16384, D=16, K=64
//   s  = scaling[0,0,:,0]            (D,)
//   Hx = x * s                       (B,N,D)
//   Cs = s[:,None] * centers.T      -> scaled centers, (K,D) row-major here
//   O[b,n,k] = sum_d (Hx[b,n,d] - s[d]*centers[k,d])^2
// Outputs concatenated: O (B*N*K floats) then Hx (B*N*D floats).

constexpr int D = 16;
constexpr int K = 64;
constexpr int ROWS_PER_BLOCK = 32;   // 8 iterations x 4 row-groups
constexpr int BLOCK = 256;

__global__ __launch_bounds__(BLOCK) void rbf_kernel(
    const float* __restrict__ x,        // (rows, D)
    const float* __restrict__ centers,  // (K, D)
    const float* __restrict__ scaling,  // (D,)  [from (1,1,D,1)]
    float* __restrict__ O,              // (rows, K)
    float* __restrict__ Hx,             // (rows, D)
    int nRows)
{
    const int tid  = threadIdx.x;
    const int lane = tid & 63;          // = center index k
    const int rgrp = tid >> 6;          // 0..3 row-group within block

    __shared__ float x_sh[ROWS_PER_BLOCK * D];  // 512 floats
    __shared__ float s_sh[D];

    const int blockRow0 = blockIdx.x * ROWS_PER_BLOCK;

    if (tid < D) s_sh[tid] = scaling[tid];

    // Stage 32 rows of x (512 floats) with one float2 per thread.
    {
        const float2* xsrc = reinterpret_cast<const float2*>(x + (size_t)blockRow0 * D);
        float2 v = xsrc[tid];
        x_sh[2 * tid]     = v.x;
        x_sh[2 * tid + 1] = v.y;
    }
    __syncthreads();

    // Per-lane scaled center row in registers (16 VGPRs), float4 loads.
    float cs[D];
    {
        const float4* c4 = reinterpret_cast<const float4*>(centers + lane * D);
        #pragma unroll
        for (int q = 0; q < 4; ++q) {
            float4 v = c4[q];
            cs[4 * q + 0] = v.x * s_sh[4 * q + 0];
            cs[4 * q + 1] = v.y * s_sh[4 * q + 1];
            cs[4 * q + 2] = v.z * s_sh[4 * q + 2];
            cs[4 * q + 3] = v.w * s_sh[4 * q + 3];
        }
    }

    // 8 iterations, each wave handles one row per iteration.
    #pragma unroll
    for (int r = 0; r < ROWS_PER_BLOCK / 4; ++r) {
        const int localRow = r * 4 + rgrp;
        const int row = blockRow0 + localRow;
        if (row >= nRows) break;

        float acc = 0.f;
        #pragma unroll
        for (int d = 0; d < D; ++d) {
            float hx = x_sh[localRow * D + d] * s_sh[d];   // LDS broadcast
            float diff = hx - cs[d];
            acc = fmaf(diff, diff, acc);
        }
        O[(size_t)row * K + lane] = acc;   // per-wave 256B contiguous store
    }

    // Hx writes: 512 values, 2 per thread, coalesced.
    #pragma unroll
    for (int i = tid; i < ROWS_PER_BLOCK * D; i += BLOCK) {
        int row = blockRow0 + (i >> 4);
        if (row < nRows)
            Hx[(size_t)blockRow0 * D + i] = x_sh[i] * s_sh[i & (D - 1)];
    }
}

extern "C" void kernel_launch(void* const* d_in, const int* in_sizes, int n_in,
                              void* d_out, int out_size, void* d_ws, size_t ws_size,
                              hipStream_t stream) {
    const float* x       = (const float*)d_in[0];
    const float* centers = (const float*)d_in[1];
    const float* scaling = (const float*)d_in[2];

    const int nRows = in_sizes[0] / D;          // B*N = 65536
    float* O  = (float*)d_out;                  // nRows*K floats
    float* Hx = (float*)d_out + (size_t)nRows * K;

    const int grid = (nRows + ROWS_PER_BLOCK - 1) / ROWS_PER_BLOCK;  // 2048
    rbf_kernel<<<grid, BLOCK, 0, stream>>>(x, centers, scaling, O, Hx, nRows);
}

// Round 2
// 12.833 us; speedup vs baseline: 1.0238x; 1.0238x over previous
//
#include <hip/hip_runtime.h>

// RBFLayer: B=4, N=16384, D=16, K=64
//   s  = scaling[0,0,:,0]            (D,)
//   Hx = x * s                       (B,N,D)
//   O[b,n,k] = sum_d (Hx[b,n,d] - s[d]*centers[k,d])^2
// Outputs concatenated: O (B*N*K floats) then Hx (B*N*D floats).

constexpr int D = 16;
constexpr int K = 64;
constexpr int ROWS_PER_BLOCK = 32;
constexpr int BLOCK = 256;

__global__ __launch_bounds__(BLOCK) void rbf_kernel(
    const float* __restrict__ x,        // (rows, D)
    const float* __restrict__ centers,  // (K, D)
    const float* __restrict__ scaling,  // (D,)
    float* __restrict__ O,              // (rows, K)
    float* __restrict__ Hx,             // (rows, D)
    int nRows)
{
    const int tid  = threadIdx.x;
    const int lane = tid & 63;          // = center index k
    const int rgrp = tid >> 6;          // 0..3 row-group within block

    __shared__ float hx_sh[ROWS_PER_BLOCK * D];   // 2 KB, holds Hx tile

    const int blockRow0 = blockIdx.x * ROWS_PER_BLOCK;

    // ---- Staging: load x tile (512 floats, float2/thread), scale once,
    //      write to LDS and straight to global Hx (coalesced float2). ----
    {
        const float2* xsrc = reinterpret_cast<const float2*>(x + (size_t)blockRow0 * D);
        const float2* s2p  = reinterpret_cast<const float2*>(scaling);
        float2 v  = xsrc[tid];
        float2 s2 = s2p[tid & 7];        // which float2 within the 16-wide row
        float2 h;
        h.x = v.x * s2.x;
        h.y = v.y * s2.y;
        reinterpret_cast<float2*>(hx_sh)[tid] = h;
        reinterpret_cast<float2*>(Hx + (size_t)blockRow0 * D)[tid] = h;
    }

    // ---- Per-lane scaled center row in registers (16 VGPRs). ----
    float cs[D];
    {
        const float4* c4 = reinterpret_cast<const float4*>(centers + lane * D);
        const float4* s4 = reinterpret_cast<const float4*>(scaling);
        #pragma unroll
        for (int q = 0; q < 4; ++q) {
            float4 cv = c4[q];
            float4 sv = s4[q];           // 64B array, L1-broadcast
            cs[4 * q + 0] = cv.x * sv.x;
            cs[4 * q + 1] = cv.y * sv.y;
            cs[4 * q + 2] = cv.z * sv.z;
            cs[4 * q + 3] = cv.w * sv.w;
        }
    }

    __syncthreads();

    // ---- Main loop: 8 iterations, one row per wave per iteration.
    //      4 x ds_read_b128 broadcast + 16 sub + 16 fma per row. ----
    const float4* hx4 = reinterpret_cast<const float4*>(hx_sh);
    #pragma unroll
    for (int r = 0; r < ROWS_PER_BLOCK / 4; ++r) {
        const int localRow = r * 4 + rgrp;
        const int row = blockRow0 + localRow;
        if (row >= nRows) break;

        float4 h0 = hx4[localRow * 4 + 0];
        float4 h1 = hx4[localRow * 4 + 1];
        float4 h2 = hx4[localRow * 4 + 2];
        float4 h3 = hx4[localRow * 4 + 3];

        float acc = 0.f;
        float d0;
        d0 = h0.x - cs[0];  acc = fmaf(d0, d0, acc);
        d0 = h0.y - cs[1];  acc = fmaf(d0, d0, acc);
        d0 = h0.z - cs[2];  acc = fmaf(d0, d0, acc);
        d0 = h0.w - cs[3];  acc = fmaf(d0, d0, acc);
        d0 = h1.x - cs[4];  acc = fmaf(d0, d0, acc);
        d0 = h1.y - cs[5];  acc = fmaf(d0, d0, acc);
        d0 = h1.z - cs[6];  acc = fmaf(d0, d0, acc);
        d0 = h1.w - cs[7];  acc = fmaf(d0, d0, acc);
        d0 = h2.x - cs[8];  acc = fmaf(d0, d0, acc);
        d0 = h2.y - cs[9];  acc = fmaf(d0, d0, acc);
        d0 = h2.z - cs[10]; acc = fmaf(d0, d0, acc);
        d0 = h2.w - cs[11]; acc = fmaf(d0, d0, acc);
        d0 = h3.x - cs[12]; acc = fmaf(d0, d0, acc);
        d0 = h3.y - cs[13]; acc = fmaf(d0, d0, acc);
        d0 = h3.z - cs[14]; acc = fmaf(d0, d0, acc);
        d0 = h3.w - cs[15]; acc = fmaf(d0, d0, acc);

        O[(size_t)row * K + lane] = acc;   // 256B contiguous per wave
    }
}

extern "C" void kernel_launch(void* const* d_in, const int* in_sizes, int n_in,
                              void* d_out, int out_size, void* d_ws, size_t ws_size,
                              hipStream_t stream) {
    const float* x       = (const float*)d_in[0];
    const float* centers = (const float*)d_in[1];
    const float* scaling = (const float*)d_in[2];

    const int nRows = in_sizes[0] / D;          // B*N = 65536
    float* O  = (float*)d_out;                  // nRows*K floats
    float* Hx = (float*)d_out + (size_t)nRows * K;

    const int grid = (nRows + ROWS_PER_BLOCK - 1) / ROWS_PER_BLOCK;  // 2048
    rbf_kernel<<<grid, BLOCK, 0, stream>>>(x, centers, scaling, O, Hx, nRows);
}